// Round 13
// baseline (304.839 us; speedup 1.0000x reference)
//
#include <hip/hip_runtime.h>
#include <hip/hip_fp16.h>
#include <math.h>

// GCN 2-layer. norm_e = dinv[src]*dinv[dst] factorizes: pre-scale at source
// (gemm1 epilogue), aggregate raw, post-scale at destination.
// Proven structure (R10/R11, 276 us): window-partitioned pairs via LDS FIFO
// (chunked writes, amp~1) -> block-local CSR fill -> CSR wave-per-node gather.
// R12: agg1 is line-throughput-bound (R11 A/B: 2x MLP -> 0 change; 1.46
// lines/edge at 2.9 TB/s). Halve lines: h1 rows packed to ONE 64 B line as
// 50x int8 + fp32 per-row scale @ byte 52 (scale=dinv*rowmax/127, quantized
// in gemm1 epilogue; di cancels in quantizer). Err ~1e-3 << 1.55e-2 thr.

constexpr int N    = 100000;
constexpr int E    = 3200000;
constexpr int F_IN = 128;
constexpr int H    = 50;
constexpr int RB   = 64;                  // packed h1 row bytes (1 line)

constexpr int WSH  = 8;                   // window shift: 256 nodes
constexpr int WSZ  = 1 << WSH;
constexpr int NW   = (N + WSZ - 1) / WSZ; // 391 windows
constexpr int CAP  = 24;                  // FIFO capacity per window bin
constexpr int PART_BLK = 512;

constexpr int XS_LD = F_IN + 4;
constexpr int WS_LD = 64;

typedef int int4v __attribute__((ext_vector_type(4)));
typedef unsigned uint4v __attribute__((ext_vector_type(4)));

// ---------------- build ----------------

// window histogram via LDS, grid-stride
__global__ __launch_bounds__(256) void k_coarse(const int* __restrict__ dst,
                                                int* __restrict__ bcnt) {
    __shared__ int h[NW];
    const int t = threadIdx.x;
    for (int i = t; i < NW; i += 256) h[i] = 0;
    __syncthreads();
    const int4v* dst4 = (const int4v*)dst;
    const long Q = E / 4;
    for (long q = (long)blockIdx.x * 256 + t; q < Q; q += (long)gridDim.x * 256) {
        int4v d = __builtin_nontemporal_load(dst4 + q);
        atomicAdd(&h[d.x >> WSH], 1);
        atomicAdd(&h[d.y >> WSH], 1);
        atomicAdd(&h[d.z >> WSH], 1);
        atomicAdd(&h[d.w >> WSH], 1);
    }
    __syncthreads();
    for (int i = t; i < NW; i += 256)
        if (h[i]) atomicAdd(&bcnt[i], h[i]);
}

// parallel exclusive scan of NW window counts (single block, LDS)
__global__ __launch_bounds__(512) void k_scanw(const int* __restrict__ bcnt,
                                               int* __restrict__ bptr,
                                               int* __restrict__ gcur) {
    __shared__ int tmp[512];
    const int t = threadIdx.x;
    int v = (t < NW) ? bcnt[t] : 0;
    tmp[t] = v;
    __syncthreads();
    for (int o = 1; o < 512; o <<= 1) {
        int y = (t >= o) ? tmp[t - o] : 0;
        __syncthreads();
        tmp[t] += y;
        __syncthreads();
    }
    if (t < NW) {
        int excl = tmp[t] - v;
        bptr[t] = excl;
        gcur[t] = excl;
    }
    if (t == NW - 1) bptr[NW] = tmp[t];   // == E
}

// partition edges into window bins; LDS FIFO -> contiguous chunk writes
__global__ __launch_bounds__(256) void k_part(const int* __restrict__ src,
                                              const int* __restrict__ dst,
                                              int* __restrict__ gcur,
                                              int* __restrict__ pairs) {
    __shared__ int fifo[NW][CAP];   // 37.5 KB
    __shared__ int lcnt[NW];
    const int t = threadIdx.x;
    for (int i = t; i < NW; i += 256) lcnt[i] = 0;
    __syncthreads();
    const int4v* dst4 = (const int4v*)dst;
    const int4v* src4 = (const int4v*)src;
    const long Q = E / 4;
    for (long tq = (long)blockIdx.x * 1024; tq < Q; tq += (long)gridDim.x * 1024) {
        #pragma unroll
        for (int u = 0; u < 4; ++u) {
            long q = tq + u * 256 + t;
            if (q < Q) {
                int4v d = __builtin_nontemporal_load(dst4 + q);
                int4v s = __builtin_nontemporal_load(src4 + q);
                #pragma unroll
                for (int e = 0; e < 4; ++e) {
                    int dd = (e == 0) ? d.x : (e == 1) ? d.y : (e == 2) ? d.z : d.w;
                    int ss = (e == 0) ? s.x : (e == 1) ? s.y : (e == 2) ? s.z : s.w;
                    int b  = dd >> WSH;
                    int pk = (ss << WSH) | (dd & (WSZ - 1));
                    int pos = atomicAdd(&lcnt[b], 1);
                    if (pos < CAP) fifo[b][pos] = pk;
                    else { int p = atomicAdd(&gcur[b], 1); pairs[p] = pk; }  // rare
                }
            }
        }
        __syncthreads();
        for (int b = t; b < NW; b += 256) {
            int c = lcnt[b]; if (c > CAP) c = CAP;
            if (c > 0) {
                int base = atomicAdd(&gcur[b], c);
                for (int j = 0; j < c; ++j) pairs[base + j] = fifo[b][j];
                lcnt[b] = 0;
            }
        }
        __syncthreads();
    }
}

// block per window: histogram -> scan -> rowptr/deg/dinv -> fill colidx.
__global__ __launch_bounds__(512) void k_csrfill(const int* __restrict__ pairs,
                                                 const int* __restrict__ bptr,
                                                 int* __restrict__ colidx,
                                                 int* __restrict__ rowptr,
                                                 int* __restrict__ degn,
                                                 float* __restrict__ dinv) {
    __shared__ int cnt[WSZ];
    __shared__ int cur[WSZ];
    __shared__ int wsum[4];
    const int t = threadIdx.x, w = blockIdx.x;
    if (t < WSZ) cnt[t] = 0;
    __syncthreads();
    const int p0 = bptr[w], p1 = bptr[w + 1];
    for (int i = p0 + t; i < p1; i += 512)
        atomicAdd(&cnt[pairs[i] & (WSZ - 1)], 1);
    __syncthreads();
    int v = 0, incl = 0;
    if (t < WSZ) {
        const int lane = t & 63, wid = t >> 6;
        v = cnt[t];
        incl = v;
        #pragma unroll
        for (int o = 1; o < 64; o <<= 1) {
            int y = __shfl_up(incl, o);
            if (lane >= o) incl += y;
        }
        if (lane == 63) wsum[wid] = incl;
    }
    __syncthreads();
    if (t < WSZ) {
        const int wid = t >> 6;
        int wbase = 0;
        #pragma unroll
        for (int u = 0; u < 4; ++u) wbase += (u < wid) ? wsum[u] : 0;
        int excl = wbase + incl - v;
        cur[t] = excl;
        int node = (w << WSH) + t;
        if (node < N) {
            rowptr[node] = p0 + excl;
            degn[node]   = v;
            dinv[node]   = rsqrtf((float)v + 1.0f);   // +1 self loop
        }
    }
    __syncthreads();
    for (int i = p0 + t; i < p1; i += 512) {
        int pk  = pairs[i];
        int pos = atomicAdd(&cur[pk & (WSZ - 1)], 1);
        colidx[p0 + pos] = pk >> WSH;
    }
}

// ---------------- compute ----------------

// h1 row (64 B): bytes 0..49 = int8 quantized features, float scale @ 52.
// decode: f[j] = (int8)row[j] * scale;  scale = dinv*rowmax/127.
__global__ __launch_bounds__(256, 2) void k_gemm1(const float* __restrict__ x,
                                                  const float* __restrict__ W1,
                                                  const float* __restrict__ dinv,
                                                  signed char* __restrict__ h1q) {
    __shared__ float xs[64][XS_LD];
    __shared__ float Ws[F_IN][WS_LD];
    const int t = threadIdx.x;
    const int row0 = blockIdx.x * 64;

    for (int i = t; i < F_IN * H; i += 256)
        Ws[i / H][i % H] = W1[i];
    for (int i = t; i < F_IN * (WS_LD - H); i += 256)
        Ws[i / (WS_LD - H)][H + i % (WS_LD - H)] = 0.0f;
    for (int i = t; i < 64 * (F_IN / 4); i += 256) {
        int r  = i >> 5;
        int c4 = i & 31;
        int gr = row0 + r;
        float4 v = make_float4(0.f, 0.f, 0.f, 0.f);
        if (gr < N) v = *(const float4*)(x + (long)gr * F_IN + c4 * 4);
        *(float4*)&xs[r][c4 * 4] = v;
    }
    __syncthreads();

    const int r  = t >> 2;
    const int g  = t & 3;
    const int j0 = g * 16;
    float acc[16];
    #pragma unroll
    for (int u = 0; u < 16; ++u) acc[u] = 0.0f;

    const float* xrow = &xs[r][0];
    #pragma unroll 4
    for (int k0 = 0; k0 < F_IN; k0 += 4) {
        float4 xv = *(const float4*)(xrow + k0);
        float xk[4] = {xv.x, xv.y, xv.z, xv.w};
        #pragma unroll
        for (int kk = 0; kk < 4; ++kk) {
            const float* wrow = &Ws[k0 + kk][j0];
            float4 wa = *(const float4*)(wrow);
            float4 wb = *(const float4*)(wrow + 4);
            float4 wc = *(const float4*)(wrow + 8);
            float4 wd = *(const float4*)(wrow + 12);
            float xr = xk[kk];
            acc[0]  += xr * wa.x; acc[1]  += xr * wa.y;
            acc[2]  += xr * wa.z; acc[3]  += xr * wa.w;
            acc[4]  += xr * wb.x; acc[5]  += xr * wb.y;
            acc[6]  += xr * wb.z; acc[7]  += xr * wb.w;
            acc[8]  += xr * wc.x; acc[9]  += xr * wc.y;
            acc[10] += xr * wc.z; acc[11] += xr * wc.w;
            acc[12] += xr * wd.x; acc[13] += xr * wd.y;
            acc[14] += xr * wd.z; acc[15] += xr * wd.w;
        }
    }

    int gr = row0 + r;
    if (gr >= N) return;
    float di = dinv[gr];

    // row |max| across this thread's valid j, then across the 4-thread group
    float m = 0.0f;
    #pragma unroll
    for (int u = 0; u < 16; ++u)
        if (j0 + u < H) m = fmaxf(m, fabsf(acc[u]));
    m = fmaxf(m, __shfl_xor(m, 1));
    m = fmaxf(m, __shfl_xor(m, 2));
    m = fmaxf(m, 1e-12f);
    const float qmul  = 127.0f / m;       // quantizer (di cancels)
    const float scale = di * m * (1.0f / 127.0f);

    unsigned out[4] = {0u, 0u, 0u, 0u};
    #pragma unroll
    for (int u = 0; u < 16; ++u) {
        int q = 0;
        if (j0 + u < H) {
            q = (int)rintf(acc[u] * qmul);
            q = max(-127, min(127, q));
        }
        ((signed char*)out)[u] = (signed char)q;
    }
    if (g == 3) out[1] = __float_as_uint(scale);   // byte offset 52 in row
    *(uint4v*)(h1q + (long)gr * RB + g * 16) = *(uint4v*)out;
}

// CSR wave-per-node: agg = self + sum_{nbr} h1[nbr] (int8 decode, 1 line per
// gather); z = relu(di*agg+b1); h2 = di * (z @ W2). 16 chains in flight.
__global__ __launch_bounds__(256) void k_agg1_fused(const int* __restrict__ rowptr,
                                                    const int* __restrict__ degn,
                                                    const int* __restrict__ colidx,
                                                    const signed char* __restrict__ h1q,
                                                    const float* __restrict__ dinv,
                                                    const float* __restrict__ b1,
                                                    const float* __restrict__ W2,
                                                    float* __restrict__ h2) {
    const int lane = threadIdx.x & 63;
    const bool act = lane < H;
    float b1v = act ? b1[lane] : 0.0f;
    float w20 = act ? W2[lane * 2 + 0] : 0.0f;
    float w21 = act ? W2[lane * 2 + 1] : 0.0f;

    long gw = ((long)blockIdx.x * blockDim.x + threadIdx.x) >> 6;
    long nwav = ((long)gridDim.x * blockDim.x) >> 6;
    for (long i = gw; i < N; i += nwav) {
        const int start = rowptr[i];
        const int deg   = degn[i];
        float a[16];
        #pragma unroll
        for (int u = 0; u < 16; ++u) a[u] = 0.0f;
        if (act) {   // self loop
            const signed char* row = h1q + i * RB;
            a[0] = (float)row[lane] * *(const float*)(row + 52);
        }
        int k = 0;
        for (; k + 16 <= deg; k += 16) {
            const signed char* r[16];
            #pragma unroll
            for (int u = 0; u < 16; ++u)
                r[u] = h1q + (long)colidx[start + k + u] * RB;
            if (act) {
                #pragma unroll
                for (int u = 0; u < 16; ++u)
                    a[u] += (float)r[u][lane] * *(const float*)(r[u] + 52);
            }
        }
        for (; k + 4 <= deg; k += 4) {
            const signed char* r[4];
            #pragma unroll
            for (int u = 0; u < 4; ++u)
                r[u] = h1q + (long)colidx[start + k + u] * RB;
            if (act) {
                #pragma unroll
                for (int u = 0; u < 4; ++u)
                    a[u] += (float)r[u][lane] * *(const float*)(r[u] + 52);
            }
        }
        for (; k < deg; ++k) {
            const signed char* r0 = h1q + (long)colidx[start + k] * RB;
            if (act) a[0] += (float)r0[lane] * *(const float*)(r0 + 52);
        }
        float agg = (((a[0] + a[1]) + (a[2] + a[3])) + ((a[4] + a[5]) + (a[6] + a[7])))
                  + (((a[8] + a[9]) + (a[10] + a[11])) + ((a[12] + a[13]) + (a[14] + a[15])));
        float di = dinv[i];
        float v = fmaxf(di * agg + b1v, 0.0f);
        float p0 = v * w20, p1 = v * w21;
        #pragma unroll
        for (int o = 32; o > 0; o >>= 1) {
            p0 += __shfl_xor(p0, o);
            p1 += __shfl_xor(p1, o);
        }
        if (lane == 0) {
            h2[i * 2 + 0] = di * p0;
            h2[i * 2 + 1] = di * p1;
        }
    }
}

// CSR wave-per-node, lanes over edges: out = log_softmax(di*(sum+self)+b2)
__global__ __launch_bounds__(256) void k_agg2_final(const int* __restrict__ rowptr,
                                                    const int* __restrict__ degn,
                                                    const int* __restrict__ colidx,
                                                    const float* __restrict__ h2,
                                                    const float* __restrict__ dinv,
                                                    const float* __restrict__ b2,
                                                    float* __restrict__ out) {
    const int lane = threadIdx.x & 63;
    long gw = ((long)blockIdx.x * blockDim.x + threadIdx.x) >> 6;
    long nwav = ((long)gridDim.x * blockDim.x) >> 6;
    for (long i = gw; i < N; i += nwav) {
        const int start = rowptr[i];
        const int deg   = degn[i];
        float s0 = 0.0f, s1 = 0.0f;
        for (int k = lane; k < deg; k += 64) {
            int s = colidx[start + k];
            s0 += h2[(long)s * 2 + 0];
            s1 += h2[(long)s * 2 + 1];
        }
        #pragma unroll
        for (int o = 32; o > 0; o >>= 1) {
            s0 += __shfl_xor(s0, o);
            s1 += __shfl_xor(s1, o);
        }
        if (lane == 0) {
            float di = dinv[i];
            float a0 = di * (s0 + h2[i * 2 + 0]) + b2[0];
            float a1 = di * (s1 + h2[i * 2 + 1]) + b2[1];
            float m = fmaxf(a0, a1);
            float lse = m + logf(expf(a0 - m) + expf(a1 - m));
            out[i * 2 + 0] = a0 - lse;
            out[i * 2 + 1] = a1 - lse;
        }
    }
}

extern "C" void kernel_launch(void* const* d_in, const int* in_sizes, int n_in,
                              void* d_out, int out_size, void* d_ws, size_t ws_size,
                              hipStream_t stream) {
    const float* x  = (const float*)d_in[0];
    const int*   ei = (const int*)d_in[1];   // [2][E]: row0 src, row1 dst
    const float* W1 = (const float*)d_in[2];
    const float* b1 = (const float*)d_in[3];
    const float* W2 = (const float*)d_in[4];
    const float* b2 = (const float*)d_in[5];
    float* out = (float*)d_out;

    const int* src = ei;
    const int* dst = ei + E;

    // ws layout
    int*    bcnt   = (int*)d_ws;             // 392
    int*    bptr   = bcnt + 392;             // 393
    int*    gcur   = bptr + 400;             // 392
    int*    rowptr = gcur + 400;             // N
    int*    degn   = rowptr + N;             // N
    float*  dinv   = (float*)(degn + N);     // N
    int*    pairs  = (int*)(dinv + N);       // E
    int*    colidx = pairs + E;              // E
    signed char* h1q = (signed char*)(colidx + E);     // N*64 bytes (6.4 MB)
    float*  h2     = (float*)(h1q + (long)N * RB);     // N*2  (~35 MB total)

    hipMemsetAsync(bcnt, 0, 392 * sizeof(int), stream);
    k_coarse<<<PART_BLK, 256, 0, stream>>>(dst, bcnt);
    k_scanw<<<1, 512, 0, stream>>>(bcnt, bptr, gcur);
    k_part<<<PART_BLK, 256, 0, stream>>>(src, dst, gcur, pairs);
    k_csrfill<<<NW, 512, 0, stream>>>(pairs, bptr, colidx, rowptr, degn, dinv);
    k_gemm1<<<(N + 63) / 64, 256, 0, stream>>>(x, W1, dinv, h1q);
    k_agg1_fused<<<4096, 256, 0, stream>>>(rowptr, degn, colidx, h1q, dinv, b1, W2, h2);
    k_agg2_final<<<2048, 256, 0, stream>>>(rowptr, degn, colidx, h2, dinv, b2, out);
}

// Round 14
// 242.054 us; speedup vs baseline: 1.2594x; 1.2594x over previous
//
#include <hip/hip_runtime.h>
#include <hip/hip_fp16.h>
#include <math.h>

// GCN 2-layer. norm_e = dinv[src]*dinv[dst] factorizes: pre-scale at source
// (gemm1 epilogue), aggregate raw, post-scale at destination.
// Proven structure (R10-R12): window-partitioned pairs via LDS FIFO ->
// block-local CSR fill -> CSR gather. h1 = one 64 B line per row: 50x uint8
// (biased +128) + fp32 scale @ byte 52 (scale=dinv*rowmax/127).
// R13: R12 halved FETCH (299->139 MB) but slowed down (2 VMEM instr/nbr,
// occ 38%). Now: wave processes 4 neighbors at once, lane 16n+d loads dword
// d of neighbor n's row -> 1 VMEM instr per 4 rows, full line utilization;
// scale via shfl from lane 16n+13; biased-ubyte decode with correction term
// (5 VALU/dword); feature reduce shfl_xor(16,32), W2 dot, shfl_xor(1..8).

constexpr int N    = 100000;
constexpr int E    = 3200000;
constexpr int F_IN = 128;
constexpr int H    = 50;
constexpr int RB   = 64;                  // packed h1 row bytes (1 line)

constexpr int WSH  = 8;                   // window shift: 256 nodes
constexpr int WSZ  = 1 << WSH;
constexpr int NW   = (N + WSZ - 1) / WSZ; // 391 windows
constexpr int CAP  = 24;                  // FIFO capacity per window bin
constexpr int PART_BLK = 512;

constexpr int XS_LD = F_IN + 4;
constexpr int WS_LD = 64;

typedef int int4v __attribute__((ext_vector_type(4)));
typedef unsigned uint4v __attribute__((ext_vector_type(4)));

// ---------------- build ----------------

// window histogram via LDS, grid-stride
__global__ __launch_bounds__(256) void k_coarse(const int* __restrict__ dst,
                                                int* __restrict__ bcnt) {
    __shared__ int h[NW];
    const int t = threadIdx.x;
    for (int i = t; i < NW; i += 256) h[i] = 0;
    __syncthreads();
    const int4v* dst4 = (const int4v*)dst;
    const long Q = E / 4;
    for (long q = (long)blockIdx.x * 256 + t; q < Q; q += (long)gridDim.x * 256) {
        int4v d = __builtin_nontemporal_load(dst4 + q);
        atomicAdd(&h[d.x >> WSH], 1);
        atomicAdd(&h[d.y >> WSH], 1);
        atomicAdd(&h[d.z >> WSH], 1);
        atomicAdd(&h[d.w >> WSH], 1);
    }
    __syncthreads();
    for (int i = t; i < NW; i += 256)
        if (h[i]) atomicAdd(&bcnt[i], h[i]);
}

// parallel exclusive scan of NW window counts (single block, LDS)
__global__ __launch_bounds__(512) void k_scanw(const int* __restrict__ bcnt,
                                               int* __restrict__ bptr,
                                               int* __restrict__ gcur) {
    __shared__ int tmp[512];
    const int t = threadIdx.x;
    int v = (t < NW) ? bcnt[t] : 0;
    tmp[t] = v;
    __syncthreads();
    for (int o = 1; o < 512; o <<= 1) {
        int y = (t >= o) ? tmp[t - o] : 0;
        __syncthreads();
        tmp[t] += y;
        __syncthreads();
    }
    if (t < NW) {
        int excl = tmp[t] - v;
        bptr[t] = excl;
        gcur[t] = excl;
    }
    if (t == NW - 1) bptr[NW] = tmp[t];   // == E
}

// partition edges into window bins; LDS FIFO -> contiguous chunk writes
__global__ __launch_bounds__(256) void k_part(const int* __restrict__ src,
                                              const int* __restrict__ dst,
                                              int* __restrict__ gcur,
                                              int* __restrict__ pairs) {
    __shared__ int fifo[NW][CAP];   // 37.5 KB
    __shared__ int lcnt[NW];
    const int t = threadIdx.x;
    for (int i = t; i < NW; i += 256) lcnt[i] = 0;
    __syncthreads();
    const int4v* dst4 = (const int4v*)dst;
    const int4v* src4 = (const int4v*)src;
    const long Q = E / 4;
    for (long tq = (long)blockIdx.x * 1024; tq < Q; tq += (long)gridDim.x * 1024) {
        #pragma unroll
        for (int u = 0; u < 4; ++u) {
            long q = tq + u * 256 + t;
            if (q < Q) {
                int4v d = __builtin_nontemporal_load(dst4 + q);
                int4v s = __builtin_nontemporal_load(src4 + q);
                #pragma unroll
                for (int e = 0; e < 4; ++e) {
                    int dd = (e == 0) ? d.x : (e == 1) ? d.y : (e == 2) ? d.z : d.w;
                    int ss = (e == 0) ? s.x : (e == 1) ? s.y : (e == 2) ? s.z : s.w;
                    int b  = dd >> WSH;
                    int pk = (ss << WSH) | (dd & (WSZ - 1));
                    int pos = atomicAdd(&lcnt[b], 1);
                    if (pos < CAP) fifo[b][pos] = pk;
                    else { int p = atomicAdd(&gcur[b], 1); pairs[p] = pk; }  // rare
                }
            }
        }
        __syncthreads();
        for (int b = t; b < NW; b += 256) {
            int c = lcnt[b]; if (c > CAP) c = CAP;
            if (c > 0) {
                int base = atomicAdd(&gcur[b], c);
                for (int j = 0; j < c; ++j) pairs[base + j] = fifo[b][j];
                lcnt[b] = 0;
            }
        }
        __syncthreads();
    }
}

// block per window: histogram -> scan -> rowptr/deg/dinv -> fill colidx.
__global__ __launch_bounds__(512) void k_csrfill(const int* __restrict__ pairs,
                                                 const int* __restrict__ bptr,
                                                 int* __restrict__ colidx,
                                                 int* __restrict__ rowptr,
                                                 int* __restrict__ degn,
                                                 float* __restrict__ dinv) {
    __shared__ int cnt[WSZ];
    __shared__ int cur[WSZ];
    __shared__ int wsum[4];
    const int t = threadIdx.x, w = blockIdx.x;
    if (t < WSZ) cnt[t] = 0;
    __syncthreads();
    const int p0 = bptr[w], p1 = bptr[w + 1];
    for (int i = p0 + t; i < p1; i += 512)
        atomicAdd(&cnt[pairs[i] & (WSZ - 1)], 1);
    __syncthreads();
    int v = 0, incl = 0;
    if (t < WSZ) {
        const int lane = t & 63, wid = t >> 6;
        v = cnt[t];
        incl = v;
        #pragma unroll
        for (int o = 1; o < 64; o <<= 1) {
            int y = __shfl_up(incl, o);
            if (lane >= o) incl += y;
        }
        if (lane == 63) wsum[wid] = incl;
    }
    __syncthreads();
    if (t < WSZ) {
        const int wid = t >> 6;
        int wbase = 0;
        #pragma unroll
        for (int u = 0; u < 4; ++u) wbase += (u < wid) ? wsum[u] : 0;
        int excl = wbase + incl - v;
        cur[t] = excl;
        int node = (w << WSH) + t;
        if (node < N) {
            rowptr[node] = p0 + excl;
            degn[node]   = v;
            dinv[node]   = rsqrtf((float)v + 1.0f);   // +1 self loop
        }
    }
    __syncthreads();
    for (int i = p0 + t; i < p1; i += 512) {
        int pk  = pairs[i];
        int pos = atomicAdd(&cur[pk & (WSZ - 1)], 1);
        colidx[p0 + pos] = pk >> WSH;
    }
}

// ---------------- compute ----------------

// h1 row (64 B): bytes 0..49 = uint8 (q+128), float scale @ byte 52.
// decode: f[j] = ((u8)row[j] - 128) * scale;  scale = dinv*rowmax/127.
__global__ __launch_bounds__(256, 2) void k_gemm1(const float* __restrict__ x,
                                                  const float* __restrict__ W1,
                                                  const float* __restrict__ dinv,
                                                  unsigned char* __restrict__ h1q) {
    __shared__ float xs[64][XS_LD];
    __shared__ float Ws[F_IN][WS_LD];
    const int t = threadIdx.x;
    const int row0 = blockIdx.x * 64;

    for (int i = t; i < F_IN * H; i += 256)
        Ws[i / H][i % H] = W1[i];
    for (int i = t; i < F_IN * (WS_LD - H); i += 256)
        Ws[i / (WS_LD - H)][H + i % (WS_LD - H)] = 0.0f;
    for (int i = t; i < 64 * (F_IN / 4); i += 256) {
        int r  = i >> 5;
        int c4 = i & 31;
        int gr = row0 + r;
        float4 v = make_float4(0.f, 0.f, 0.f, 0.f);
        if (gr < N) v = *(const float4*)(x + (long)gr * F_IN + c4 * 4);
        *(float4*)&xs[r][c4 * 4] = v;
    }
    __syncthreads();

    const int r  = t >> 2;
    const int g  = t & 3;
    const int j0 = g * 16;
    float acc[16];
    #pragma unroll
    for (int u = 0; u < 16; ++u) acc[u] = 0.0f;

    const float* xrow = &xs[r][0];
    #pragma unroll 4
    for (int k0 = 0; k0 < F_IN; k0 += 4) {
        float4 xv = *(const float4*)(xrow + k0);
        float xk[4] = {xv.x, xv.y, xv.z, xv.w};
        #pragma unroll
        for (int kk = 0; kk < 4; ++kk) {
            const float* wrow = &Ws[k0 + kk][j0];
            float4 wa = *(const float4*)(wrow);
            float4 wb = *(const float4*)(wrow + 4);
            float4 wc = *(const float4*)(wrow + 8);
            float4 wd = *(const float4*)(wrow + 12);
            float xr = xk[kk];
            acc[0]  += xr * wa.x; acc[1]  += xr * wa.y;
            acc[2]  += xr * wa.z; acc[3]  += xr * wa.w;
            acc[4]  += xr * wb.x; acc[5]  += xr * wb.y;
            acc[6]  += xr * wb.z; acc[7]  += xr * wb.w;
            acc[8]  += xr * wc.x; acc[9]  += xr * wc.y;
            acc[10] += xr * wc.z; acc[11] += xr * wc.w;
            acc[12] += xr * wd.x; acc[13] += xr * wd.y;
            acc[14] += xr * wd.z; acc[15] += xr * wd.w;
        }
    }

    int gr = row0 + r;
    if (gr >= N) return;
    float di = dinv[gr];

    // row |max| across this thread's valid j, then across the 4-thread group
    float m = 0.0f;
    #pragma unroll
    for (int u = 0; u < 16; ++u)
        if (j0 + u < H) m = fmaxf(m, fabsf(acc[u]));
    m = fmaxf(m, __shfl_xor(m, 1));
    m = fmaxf(m, __shfl_xor(m, 2));
    m = fmaxf(m, 1e-12f);
    const float qmul  = 127.0f / m;       // quantizer (di cancels)
    const float scale = di * m * (1.0f / 127.0f);

    unsigned out[4] = {0u, 0u, 0u, 0u};
    #pragma unroll
    for (int u = 0; u < 16; ++u) {
        int q = 128;                       // bias: pad bytes decode to 0
        if (j0 + u < H) {
            int qi = (int)rintf(acc[u] * qmul);
            qi = max(-127, min(127, qi));
            q = qi + 128;
        }
        ((unsigned char*)out)[u] = (unsigned char)q;
    }
    if (g == 3) out[1] = __float_as_uint(scale);   // byte offset 52 (dword 13)
    *(uint4v*)(h1q + (long)gr * RB + g * 16) = *(uint4v*)out;
}

// CSR gather, 4 neighbors per wave step: lane = 16n+d loads dword d of
// neighbor n's 64 B row. Biased-ubyte decode with correction term.
// z = relu(di*agg+b1); h2 = di * (z @ W2).
__global__ __launch_bounds__(256) void k_agg1_fused(const int* __restrict__ rowptr,
                                                    const int* __restrict__ degn,
                                                    const int* __restrict__ colidx,
                                                    const unsigned char* __restrict__ h1q,
                                                    const float* __restrict__ dinv,
                                                    const float* __restrict__ b1,
                                                    const float* __restrict__ W2,
                                                    float* __restrict__ h2) {
    const int lane = threadIdx.x & 63;
    const int d = lane & 15;        // dword index in row
    const int n = lane >> 4;        // neighbor slot 0..3
    const int scLane = (lane & 48) | 13;

    // per-lane epilogue constants for features 4d..4d+3
    float b1v[4], w20[4], w21[4];
    #pragma unroll
    for (int j = 0; j < 4; ++j) {
        int f = 4 * d + j;
        bool vld = f < H;
        b1v[j] = vld ? b1[f] : 0.0f;
        w20[j] = vld ? W2[f * 2 + 0] : 0.0f;
        w21[j] = vld ? W2[f * 2 + 1] : 0.0f;
    }

    long gw = ((long)blockIdx.x * blockDim.x + threadIdx.x) >> 6;
    long nwav = ((long)gridDim.x * blockDim.x) >> 6;
    for (long i = gw; i < N; i += nwav) {
        const int start = rowptr[i];
        const int deg   = degn[i];
        float a0 = 0.f, a1 = 0.f, a2 = 0.f, a3 = 0.f, corr = 0.f;

        // self row: only group n==0 contributes
        {
            unsigned w = *(const unsigned*)(h1q + i * (long)RB + 4 * d);
            float sc = __uint_as_float(__shfl((int)w, scLane));
            if (n != 0) sc = 0.0f;
            a0 += (float)(w & 0xFFu) * sc;
            a1 += (float)((w >> 8) & 0xFFu) * sc;
            a2 += (float)((w >> 16) & 0xFFu) * sc;
            a3 += (float)(w >> 24) * sc;
            corr += sc;
        }
        int k = 0;
        for (; k + 8 <= deg; k += 8) {              // 2 independent 4-row loads
            int ia = colidx[start + k + n];
            int ib = colidx[start + k + 4 + n];
            unsigned wa = *(const unsigned*)(h1q + (long)ia * RB + 4 * d);
            unsigned wb = *(const unsigned*)(h1q + (long)ib * RB + 4 * d);
            float sa = __uint_as_float(__shfl((int)wa, scLane));
            float sb = __uint_as_float(__shfl((int)wb, scLane));
            a0 += (float)(wa & 0xFFu) * sa;
            a1 += (float)((wa >> 8) & 0xFFu) * sa;
            a2 += (float)((wa >> 16) & 0xFFu) * sa;
            a3 += (float)(wa >> 24) * sa;
            corr += sa;
            a0 += (float)(wb & 0xFFu) * sb;
            a1 += (float)((wb >> 8) & 0xFFu) * sb;
            a2 += (float)((wb >> 16) & 0xFFu) * sb;
            a3 += (float)(wb >> 24) * sb;
            corr += sb;
        }
        for (; k < deg; k += 4) {
            int kk = k + n;
            int idx = colidx[start + min(kk, deg - 1)];
            unsigned w = *(const unsigned*)(h1q + (long)idx * RB + 4 * d);
            float sc = __uint_as_float(__shfl((int)w, scLane));
            if (kk >= deg) sc = 0.0f;
            a0 += (float)(w & 0xFFu) * sc;
            a1 += (float)((w >> 8) & 0xFFu) * sc;
            a2 += (float)((w >> 16) & 0xFFu) * sc;
            a3 += (float)(w >> 24) * sc;
            corr += sc;
        }
        // remove bias: f = a - 128*corr (per-lane, before group reduce)
        a0 -= 128.0f * corr;
        a1 -= 128.0f * corr;
        a2 -= 128.0f * corr;
        a3 -= 128.0f * corr;
        // reduce across the 4 neighbor groups
        #pragma unroll
        for (int o = 16; o <= 32; o <<= 1) {
            a0 += __shfl_xor(a0, o);
            a1 += __shfl_xor(a1, o);
            a2 += __shfl_xor(a2, o);
            a3 += __shfl_xor(a3, o);
        }
        float di = dinv[i];
        float z0 = fmaxf(di * a0 + b1v[0], 0.0f);
        float z1 = fmaxf(di * a1 + b1v[1], 0.0f);
        float z2 = fmaxf(di * a2 + b1v[2], 0.0f);
        float z3 = fmaxf(di * a3 + b1v[3], 0.0f);
        float p0 = z0 * w20[0] + z1 * w20[1] + z2 * w20[2] + z3 * w20[3];
        float p1 = z0 * w21[0] + z1 * w21[1] + z2 * w21[2] + z3 * w21[3];
        #pragma unroll
        for (int o = 1; o <= 8; o <<= 1) {
            p0 += __shfl_xor(p0, o);
            p1 += __shfl_xor(p1, o);
        }
        if (lane == 0) {
            h2[i * 2 + 0] = di * p0;
            h2[i * 2 + 1] = di * p1;
        }
    }
}

// CSR wave-per-node, lanes over edges: out = log_softmax(di*(sum+self)+b2)
__global__ __launch_bounds__(256) void k_agg2_final(const int* __restrict__ rowptr,
                                                    const int* __restrict__ degn,
                                                    const int* __restrict__ colidx,
                                                    const float* __restrict__ h2,
                                                    const float* __restrict__ dinv,
                                                    const float* __restrict__ b2,
                                                    float* __restrict__ out) {
    const int lane = threadIdx.x & 63;
    long gw = ((long)blockIdx.x * blockDim.x + threadIdx.x) >> 6;
    long nwav = ((long)gridDim.x * blockDim.x) >> 6;
    for (long i = gw; i < N; i += nwav) {
        const int start = rowptr[i];
        const int deg   = degn[i];
        float s0 = 0.0f, s1 = 0.0f;
        for (int k = lane; k < deg; k += 64) {
            int s = colidx[start + k];
            s0 += h2[(long)s * 2 + 0];
            s1 += h2[(long)s * 2 + 1];
        }
        #pragma unroll
        for (int o = 32; o > 0; o >>= 1) {
            s0 += __shfl_xor(s0, o);
            s1 += __shfl_xor(s1, o);
        }
        if (lane == 0) {
            float di = dinv[i];
            float a0 = di * (s0 + h2[i * 2 + 0]) + b2[0];
            float a1 = di * (s1 + h2[i * 2 + 1]) + b2[1];
            float m = fmaxf(a0, a1);
            float lse = m + logf(expf(a0 - m) + expf(a1 - m));
            out[i * 2 + 0] = a0 - lse;
            out[i * 2 + 1] = a1 - lse;
        }
    }
}

extern "C" void kernel_launch(void* const* d_in, const int* in_sizes, int n_in,
                              void* d_out, int out_size, void* d_ws, size_t ws_size,
                              hipStream_t stream) {
    const float* x  = (const float*)d_in[0];
    const int*   ei = (const int*)d_in[1];   // [2][E]: row0 src, row1 dst
    const float* W1 = (const float*)d_in[2];
    const float* b1 = (const float*)d_in[3];
    const float* W2 = (const float*)d_in[4];
    const float* b2 = (const float*)d_in[5];
    float* out = (float*)d_out;

    const int* src = ei;
    const int* dst = ei + E;

    // ws layout
    int*    bcnt   = (int*)d_ws;             // 392
    int*    bptr   = bcnt + 392;             // 393
    int*    gcur   = bptr + 400;             // 392
    int*    rowptr = gcur + 400;             // N
    int*    degn   = rowptr + N;             // N
    float*  dinv   = (float*)(degn + N);     // N
    int*    pairs  = (int*)(dinv + N);       // E
    int*    colidx = pairs + E;              // E
    unsigned char* h1q = (unsigned char*)(colidx + E);  // N*64 bytes (6.4 MB)
    float*  h2     = (float*)(h1q + (long)N * RB);      // N*2  (~35 MB total)

    hipMemsetAsync(bcnt, 0, 392 * sizeof(int), stream);
    k_coarse<<<PART_BLK, 256, 0, stream>>>(dst, bcnt);
    k_scanw<<<1, 512, 0, stream>>>(bcnt, bptr, gcur);
    k_part<<<PART_BLK, 256, 0, stream>>>(src, dst, gcur, pairs);
    k_csrfill<<<NW, 512, 0, stream>>>(pairs, bptr, colidx, rowptr, degn, dinv);
    k_gemm1<<<(N + 63) / 64, 256, 0, stream>>>(x, W1, dinv, h1q);
    k_agg1_fused<<<4096, 256, 0, stream>>>(rowptr, degn, colidx, h1q, dinv, b1, W2, h2);
    k_agg2_final<<<2048, 256, 0, stream>>>(rowptr, degn, colidx, h2, dinv, b2, out);
}

// Round 15
// 193.677 us; speedup vs baseline: 1.5740x; 1.2498x over previous
//
#include <hip/hip_runtime.h>
#include <hip/hip_fp16.h>
#include <math.h>

// GCN 2-layer. norm_e = dinv[src]*dinv[dst] factorizes: pre-scale at source
// (gemm1 epilogue), aggregate raw, post-scale at destination.
// Proven (R10-R14, 242 us): window-partitioned pairs via LDS FIFO (chunked
// writes, amp~1) -> block-local CSR fill -> CSR gather with 4-neighbor
// coalesced dword loads over 64 B int8+scale h1 rows.
// R15: (a) fixed per-window pair regions (CAPW=9216 >> 11 sigma of Poisson
// window counts) delete k_coarse + k_scanw (one full 25.6 MB edge pass).
// (b) gemm1 was LDS-instr-bound (4.25 b128 / 32 VALU cyc per wave-k):
// drop xs LDS tile, thread owns 2 rows in registers x 16 j -> VALU-bound.

constexpr int N    = 100000;
constexpr int E    = 3200000;
constexpr int F_IN = 128;
constexpr int H    = 50;
constexpr int RB   = 64;                  // packed h1 row bytes (1 line)

constexpr int WSH  = 8;                   // window shift: 256 nodes
constexpr int WSZ  = 1 << WSH;
constexpr int NW   = (N + WSZ - 1) / WSZ; // 391 windows
constexpr int CAP  = 24;                  // FIFO capacity per window bin
constexpr int CAPW = 9216;                // fixed pair-region per window
constexpr int PART_BLK = 512;

constexpr int WS_LD = 64;

typedef int int4v __attribute__((ext_vector_type(4)));
typedef unsigned uint4v __attribute__((ext_vector_type(4)));

// ---------------- build ----------------

__global__ __launch_bounds__(512) void k_init(int* __restrict__ gcur) {
    int i = threadIdx.x;
    if (i < NW) gcur[i] = i * CAPW;
}

// partition edges into fixed window regions; LDS FIFO -> contiguous chunks
__global__ __launch_bounds__(256) void k_part(const int* __restrict__ src,
                                              const int* __restrict__ dst,
                                              int* __restrict__ gcur,
                                              int* __restrict__ pairs) {
    __shared__ int fifo[NW][CAP];   // 37.5 KB
    __shared__ int lcnt[NW];
    const int t = threadIdx.x;
    for (int i = t; i < NW; i += 256) lcnt[i] = 0;
    __syncthreads();
    const int4v* dst4 = (const int4v*)dst;
    const int4v* src4 = (const int4v*)src;
    const long Q = E / 4;
    for (long tq = (long)blockIdx.x * 1024; tq < Q; tq += (long)gridDim.x * 1024) {
        #pragma unroll
        for (int u = 0; u < 4; ++u) {
            long q = tq + u * 256 + t;
            if (q < Q) {
                int4v d = __builtin_nontemporal_load(dst4 + q);
                int4v s = __builtin_nontemporal_load(src4 + q);
                #pragma unroll
                for (int e = 0; e < 4; ++e) {
                    int dd = (e == 0) ? d.x : (e == 1) ? d.y : (e == 2) ? d.z : d.w;
                    int ss = (e == 0) ? s.x : (e == 1) ? s.y : (e == 2) ? s.z : s.w;
                    int b  = dd >> WSH;
                    int pk = (ss << WSH) | (dd & (WSZ - 1));
                    int pos = atomicAdd(&lcnt[b], 1);
                    if (pos < CAP) fifo[b][pos] = pk;
                    else { int p = atomicAdd(&gcur[b], 1); pairs[p] = pk; }  // rare
                }
            }
        }
        __syncthreads();
        for (int b = t; b < NW; b += 256) {
            int c = lcnt[b]; if (c > CAP) c = CAP;
            if (c > 0) {
                int base = atomicAdd(&gcur[b], c);
                for (int j = 0; j < c; ++j) pairs[base + j] = fifo[b][j];
                lcnt[b] = 0;
            }
        }
        __syncthreads();
    }
}

// block per window: histogram -> scan -> rowptr/deg/dinv -> fill colidx.
// region [w*CAPW, gcur[w]) ; scattered stores stay in one CU's L2.
__global__ __launch_bounds__(512) void k_csrfill(const int* __restrict__ pairs,
                                                 const int* __restrict__ gcur,
                                                 int* __restrict__ colidx,
                                                 int* __restrict__ rowptr,
                                                 int* __restrict__ degn,
                                                 float* __restrict__ dinv) {
    __shared__ int cnt[WSZ];
    __shared__ int cur[WSZ];
    __shared__ int wsum[4];
    const int t = threadIdx.x, w = blockIdx.x;
    if (t < WSZ) cnt[t] = 0;
    __syncthreads();
    const int p0 = w * CAPW, p1 = gcur[w];
    for (int i = p0 + t; i < p1; i += 512)
        atomicAdd(&cnt[pairs[i] & (WSZ - 1)], 1);
    __syncthreads();
    int v = 0, incl = 0;
    if (t < WSZ) {
        const int lane = t & 63, wid = t >> 6;
        v = cnt[t];
        incl = v;
        #pragma unroll
        for (int o = 1; o < 64; o <<= 1) {
            int y = __shfl_up(incl, o);
            if (lane >= o) incl += y;
        }
        if (lane == 63) wsum[wid] = incl;
    }
    __syncthreads();
    if (t < WSZ) {
        const int wid = t >> 6;
        int wbase = 0;
        #pragma unroll
        for (int u = 0; u < 4; ++u) wbase += (u < wid) ? wsum[u] : 0;
        int excl = wbase + incl - v;
        cur[t] = excl;
        int node = (w << WSH) + t;
        if (node < N) {
            rowptr[node] = p0 + excl;
            degn[node]   = v;
            dinv[node]   = rsqrtf((float)v + 1.0f);   // +1 self loop
        }
    }
    __syncthreads();
    for (int i = p0 + t; i < p1; i += 512) {
        int pk  = pairs[i];
        int pos = atomicAdd(&cur[pk & (WSZ - 1)], 1);
        colidx[p0 + pos] = pk >> WSH;
    }
}

// ---------------- compute ----------------

// h1 row (64 B): bytes 0..49 = uint8 (q+128), float scale @ byte 52.
// R15: no xs LDS -- thread owns 2 rows (registers), 16 j; W1 in LDS only.
__global__ __launch_bounds__(256) void k_gemm1(const float* __restrict__ x,
                                               const float* __restrict__ W1,
                                               const float* __restrict__ dinv,
                                               unsigned char* __restrict__ h1q) {
    __shared__ float Ws[F_IN][WS_LD];   // 32 KB, j padded to 64
    const int t = threadIdx.x;
    for (int i = t; i < F_IN * H; i += 256)
        Ws[i / H][i % H] = W1[i];
    for (int i = t; i < F_IN * (WS_LD - H); i += 256)
        Ws[i / (WS_LD - H)][H + i % (WS_LD - H)] = 0.0f;
    __syncthreads();

    const int jg = t & 3, rq = t >> 2;
    const int j0 = jg * 16;
    const long r0 = (long)blockIdx.x * 128 + rq * 2;
    if (r0 >= N) return;
    const bool v1 = (r0 + 1 < N);

    float acc0[16], acc1[16];
    #pragma unroll
    for (int u = 0; u < 16; ++u) { acc0[u] = 0.0f; acc1[u] = 0.0f; }

    const float* xr0 = x + r0 * F_IN;
    const float* xr1 = xr0 + (v1 ? F_IN : 0);

    for (int k0 = 0; k0 < F_IN; k0 += 4) {
        float4 xa = *(const float4*)(xr0 + k0);
        float4 xb = *(const float4*)(xr1 + k0);
        float ka[4] = {xa.x, xa.y, xa.z, xa.w};
        float kb[4] = {xb.x, xb.y, xb.z, xb.w};
        #pragma unroll
        for (int kk = 0; kk < 4; ++kk) {
            const float* wrow = &Ws[k0 + kk][j0];
            float4 w0 = *(const float4*)(wrow);
            float4 w1 = *(const float4*)(wrow + 4);
            float4 w2 = *(const float4*)(wrow + 8);
            float4 w3 = *(const float4*)(wrow + 12);
            float fa = ka[kk], fb = kb[kk];
            acc0[0]  += fa * w0.x; acc0[1]  += fa * w0.y;
            acc0[2]  += fa * w0.z; acc0[3]  += fa * w0.w;
            acc0[4]  += fa * w1.x; acc0[5]  += fa * w1.y;
            acc0[6]  += fa * w1.z; acc0[7]  += fa * w1.w;
            acc0[8]  += fa * w2.x; acc0[9]  += fa * w2.y;
            acc0[10] += fa * w2.z; acc0[11] += fa * w2.w;
            acc0[12] += fa * w3.x; acc0[13] += fa * w3.y;
            acc0[14] += fa * w3.z; acc0[15] += fa * w3.w;
            acc1[0]  += fb * w0.x; acc1[1]  += fb * w0.y;
            acc1[2]  += fb * w0.z; acc1[3]  += fb * w0.w;
            acc1[4]  += fb * w1.x; acc1[5]  += fb * w1.y;
            acc1[6]  += fb * w1.z; acc1[7]  += fb * w1.w;
            acc1[8]  += fb * w2.x; acc1[9]  += fb * w2.y;
            acc1[10] += fb * w2.z; acc1[11] += fb * w2.w;
            acc1[12] += fb * w3.x; acc1[13] += fb * w3.y;
            acc1[14] += fb * w3.z; acc1[15] += fb * w3.w;
        }
    }

    #pragma unroll
    for (int rr = 0; rr < 2; ++rr) {
        long gr = r0 + rr;
        if (rr == 1 && !v1) break;
        float* acc = (rr == 0) ? acc0 : acc1;
        float m = 0.0f;
        #pragma unroll
        for (int u = 0; u < 16; ++u)
            if (j0 + u < H) m = fmaxf(m, fabsf(acc[u]));
        m = fmaxf(m, __shfl_xor(m, 1));
        m = fmaxf(m, __shfl_xor(m, 2));
        m = fmaxf(m, 1e-12f);
        const float qmul  = 127.0f / m;
        const float scale = dinv[gr] * m * (1.0f / 127.0f);

        unsigned out[4] = {0u, 0u, 0u, 0u};
        #pragma unroll
        for (int u = 0; u < 16; ++u) {
            int q = 128;                   // bias: pad bytes decode to 0
            if (j0 + u < H) {
                int qi = (int)rintf(acc[u] * qmul);
                qi = max(-127, min(127, qi));
                q = qi + 128;
            }
            ((unsigned char*)out)[u] = (unsigned char)q;
        }
        if (jg == 3) out[1] = __float_as_uint(scale);   // byte 52 of row
        *(uint4v*)(h1q + gr * RB + jg * 16) = *(uint4v*)out;
    }
}

// CSR gather, 4 neighbors per wave step: lane = 16n+d loads dword d of
// neighbor n's 64 B row. Biased-ubyte decode with correction term.
__global__ __launch_bounds__(256) void k_agg1_fused(const int* __restrict__ rowptr,
                                                    const int* __restrict__ degn,
                                                    const int* __restrict__ colidx,
                                                    const unsigned char* __restrict__ h1q,
                                                    const float* __restrict__ dinv,
                                                    const float* __restrict__ b1,
                                                    const float* __restrict__ W2,
                                                    float* __restrict__ h2) {
    const int lane = threadIdx.x & 63;
    const int d = lane & 15;        // dword index in row
    const int n = lane >> 4;        // neighbor slot 0..3
    const int scLane = (lane & 48) | 13;

    float b1v[4], w20[4], w21[4];
    #pragma unroll
    for (int j = 0; j < 4; ++j) {
        int f = 4 * d + j;
        bool vld = f < H;
        b1v[j] = vld ? b1[f] : 0.0f;
        w20[j] = vld ? W2[f * 2 + 0] : 0.0f;
        w21[j] = vld ? W2[f * 2 + 1] : 0.0f;
    }

    long gw = ((long)blockIdx.x * blockDim.x + threadIdx.x) >> 6;
    long nwav = ((long)gridDim.x * blockDim.x) >> 6;
    for (long i = gw; i < N; i += nwav) {
        const int start = rowptr[i];
        const int deg   = degn[i];
        float a0 = 0.f, a1 = 0.f, a2 = 0.f, a3 = 0.f, corr = 0.f;

        {   // self row: only group n==0 contributes
            unsigned w = *(const unsigned*)(h1q + i * (long)RB + 4 * d);
            float sc = __uint_as_float(__shfl((int)w, scLane));
            if (n != 0) sc = 0.0f;
            a0 += (float)(w & 0xFFu) * sc;
            a1 += (float)((w >> 8) & 0xFFu) * sc;
            a2 += (float)((w >> 16) & 0xFFu) * sc;
            a3 += (float)(w >> 24) * sc;
            corr += sc;
        }
        int k = 0;
        for (; k + 8 <= deg; k += 8) {              // 2 independent 4-row loads
            int ia = colidx[start + k + n];
            int ib = colidx[start + k + 4 + n];
            unsigned wa = *(const unsigned*)(h1q + (long)ia * RB + 4 * d);
            unsigned wb = *(const unsigned*)(h1q + (long)ib * RB + 4 * d);
            float sa = __uint_as_float(__shfl((int)wa, scLane));
            float sb = __uint_as_float(__shfl((int)wb, scLane));
            a0 += (float)(wa & 0xFFu) * sa;
            a1 += (float)((wa >> 8) & 0xFFu) * sa;
            a2 += (float)((wa >> 16) & 0xFFu) * sa;
            a3 += (float)(wa >> 24) * sa;
            corr += sa;
            a0 += (float)(wb & 0xFFu) * sb;
            a1 += (float)((wb >> 8) & 0xFFu) * sb;
            a2 += (float)((wb >> 16) & 0xFFu) * sb;
            a3 += (float)(wb >> 24) * sb;
            corr += sb;
        }
        for (; k < deg; k += 4) {
            int kk = k + n;
            int idx = colidx[start + min(kk, deg - 1)];
            unsigned w = *(const unsigned*)(h1q + (long)idx * RB + 4 * d);
            float sc = __uint_as_float(__shfl((int)w, scLane));
            if (kk >= deg) sc = 0.0f;
            a0 += (float)(w & 0xFFu) * sc;
            a1 += (float)((w >> 8) & 0xFFu) * sc;
            a2 += (float)((w >> 16) & 0xFFu) * sc;
            a3 += (float)(w >> 24) * sc;
            corr += sc;
        }
        a0 -= 128.0f * corr;
        a1 -= 128.0f * corr;
        a2 -= 128.0f * corr;
        a3 -= 128.0f * corr;
        #pragma unroll
        for (int o = 16; o <= 32; o <<= 1) {
            a0 += __shfl_xor(a0, o);
            a1 += __shfl_xor(a1, o);
            a2 += __shfl_xor(a2, o);
            a3 += __shfl_xor(a3, o);
        }
        float di = dinv[i];
        float z0 = fmaxf(di * a0 + b1v[0], 0.0f);
        float z1 = fmaxf(di * a1 + b1v[1], 0.0f);
        float z2 = fmaxf(di * a2 + b1v[2], 0.0f);
        float z3 = fmaxf(di * a3 + b1v[3], 0.0f);
        float p0 = z0 * w20[0] + z1 * w20[1] + z2 * w20[2] + z3 * w20[3];
        float p1 = z0 * w21[0] + z1 * w21[1] + z2 * w21[2] + z3 * w21[3];
        #pragma unroll
        for (int o = 1; o <= 8; o <<= 1) {
            p0 += __shfl_xor(p0, o);
            p1 += __shfl_xor(p1, o);
        }
        if (lane == 0) {
            h2[i * 2 + 0] = di * p0;
            h2[i * 2 + 1] = di * p1;
        }
    }
}

// CSR wave-per-node, lanes over edges: out = log_softmax(di*(sum+self)+b2)
__global__ __launch_bounds__(256) void k_agg2_final(const int* __restrict__ rowptr,
                                                    const int* __restrict__ degn,
                                                    const int* __restrict__ colidx,
                                                    const float* __restrict__ h2,
                                                    const float* __restrict__ dinv,
                                                    const float* __restrict__ b2,
                                                    float* __restrict__ out) {
    const int lane = threadIdx.x & 63;
    long gw = ((long)blockIdx.x * blockDim.x + threadIdx.x) >> 6;
    long nwav = ((long)gridDim.x * blockDim.x) >> 6;
    for (long i = gw; i < N; i += nwav) {
        const int start = rowptr[i];
        const int deg   = degn[i];
        float s0 = 0.0f, s1 = 0.0f;
        for (int k = lane; k < deg; k += 64) {
            int s = colidx[start + k];
            s0 += h2[(long)s * 2 + 0];
            s1 += h2[(long)s * 2 + 1];
        }
        #pragma unroll
        for (int o = 32; o > 0; o >>= 1) {
            s0 += __shfl_xor(s0, o);
            s1 += __shfl_xor(s1, o);
        }
        if (lane == 0) {
            float di = dinv[i];
            float a0 = di * (s0 + h2[i * 2 + 0]) + b2[0];
            float a1 = di * (s1 + h2[i * 2 + 1]) + b2[1];
            float m = fmaxf(a0, a1);
            float lse = m + logf(expf(a0 - m) + expf(a1 - m));
            out[i * 2 + 0] = a0 - lse;
            out[i * 2 + 1] = a1 - lse;
        }
    }
}

extern "C" void kernel_launch(void* const* d_in, const int* in_sizes, int n_in,
                              void* d_out, int out_size, void* d_ws, size_t ws_size,
                              hipStream_t stream) {
    const float* x  = (const float*)d_in[0];
    const int*   ei = (const int*)d_in[1];   // [2][E]: row0 src, row1 dst
    const float* W1 = (const float*)d_in[2];
    const float* b1 = (const float*)d_in[3];
    const float* W2 = (const float*)d_in[4];
    const float* b2 = (const float*)d_in[5];
    float* out = (float*)d_out;

    const int* src = ei;
    const int* dst = ei + E;

    // ws layout
    int*    gcur   = (int*)d_ws;                       // 400
    int*    rowptr = gcur + 400;                       // N
    int*    degn   = rowptr + N;                       // N
    float*  dinv   = (float*)(degn + N);               // N
    int*    pairs  = (int*)(dinv + N);                 // NW*CAPW (14.4 MB)
    int*    colidx = pairs + (long)NW * CAPW;          // NW*CAPW (14.4 MB)
    unsigned char* h1q = (unsigned char*)(colidx + (long)NW * CAPW);  // 6.4 MB
    float*  h2     = (float*)(h1q + (long)N * RB);     // N*2  (~37 MB total)

    k_init<<<1, 512, 0, stream>>>(gcur);
    k_part<<<PART_BLK, 256, 0, stream>>>(src, dst, gcur, pairs);
    k_csrfill<<<NW, 512, 0, stream>>>(pairs, gcur, colidx, rowptr, degn, dinv);
    k_gemm1<<<(N + 127) / 128, 256, 0, stream>>>(x, W1, dinv, h1q);
    k_agg1_fused<<<4096, 256, 0, stream>>>(rowptr, degn, colidx, h1q, dinv, b1, W2, h2);
    k_agg2_final<<<2048, 256, 0, stream>>>(rowptr, degn, colidx, h2, dinv, b2, out);
}